// Round 5
// baseline (121.893 us; speedup 1.0000x reference)
//
#include <hip/hip_runtime.h>

typedef __attribute__((ext_vector_type(4))) float f32x4;
typedef __bf16 bf16x8 __attribute__((ext_vector_type(8)));
typedef unsigned short ushort_t;

#define T_TOK 8192   // B*S
#define DIM   1024   // D
#define NRCOL 2048   // N_FEAT * R

#define VMW(n)  asm volatile("s_waitcnt vmcnt(" #n ")" ::: "memory")
#define SB0()   __builtin_amdgcn_sched_barrier(0)
#define BAR()   __builtin_amdgcn_s_barrier()

static __device__ __forceinline__ unsigned short f2bf(float f) {
  unsigned int u = __builtin_bit_cast(unsigned int, f);
  u += 0x7fffu + ((u >> 16) & 1u);          // RNE
  return (unsigned short)(u >> 16);
}
static __device__ __forceinline__ float bfbits2f(unsigned int lo16) {
  return __builtin_bit_cast(float, lo16 << 16);
}
static __device__ __forceinline__ void gload16(const void* g, void* l) {
  __builtin_amdgcn_global_load_lds((const __attribute__((address_space(1))) void*)g,
                                   (__attribute__((address_space(3))) void*)l, 16, 0, 0);
}

// ---------------- f32 -> bf16 straight cast (x) ----------------
__global__ __launch_bounds__(256) void cvt_f32_bf16(const float* __restrict__ in,
                                                    unsigned short* __restrict__ out,
                                                    int n4) {
  int i = blockIdx.x * 256 + threadIdx.x;
  const int stride = gridDim.x * 256;
  const float4* in4 = (const float4*)in;
  uint2* o4 = (uint2*)out;
  for (; i < n4; i += stride) {
    float4 v = in4[i];
    uint2 o;
    o.x = (unsigned)f2bf(v.x) | ((unsigned)f2bf(v.y) << 16);
    o.y = (unsigned)f2bf(v.z) | ((unsigned)f2bf(v.w) << 16);
    o4[i] = o;
  }
}

// ---------------- tiled transpose + cast ----------------
__global__ __launch_bounds__(256) void tcvt(const float* __restrict__ src,
                                            unsigned short* __restrict__ dst,
                                            int rows, int cols,
                                            long sstride, long dstride) {
  src += (size_t)blockIdx.z * sstride;
  dst += (size_t)blockIdx.z * dstride;
  __shared__ float tile[32][33];
  const int tx = threadIdx.x & 31, ty = threadIdx.x >> 5;
  const int r0 = blockIdx.y * 32, c0 = blockIdx.x * 32;
  #pragma unroll
  for (int i = 0; i < 32; i += 8)
    tile[ty + i][tx] = src[(size_t)(r0 + ty + i) * cols + c0 + tx];
  __syncthreads();
  #pragma unroll
  for (int i = 0; i < 32; i += 8)
    dst[(size_t)(c0 + ty + i) * rows + r0 + tx] = f2bf(tile[tx][ty + i]);
}

// =====================================================================
// gemmT: C[M,N] = A[M,K]*Bt[N,K]^T. 256x128 tile, BK=64, 512 thr = 8
// waves (4M x 2N, wave owns 64x64). TRIPLE-buffered LDS, ONE barrier +
// one counted vmcnt(6) per K-tile, NO explicit lgkmcnt(0): frag ds_reads
// are plain C++ loads so the compiler emits fine-grained counted lgkm
// waits interleaved into the MFMA stream. Stage(t+2) issued under tile
// t's MFMAs; vmcnt(6) retires tile t+1, leaves t+2 in flight.
// Ledger: slot(t+2)%3 == slot(t-1)%3, reads of it completed before the
// barrier ending tile t-1 (MFMA reg-deps force lgkm retirement), so the
// stage writes are write-after-read safe with one barrier per tile.
// =====================================================================
template<bool OUT_BF16>
__global__ __launch_bounds__(512, 2) void gemmT(const ushort_t* __restrict__ A,
                                                const ushort_t* __restrict__ Bt,
                                                void* __restrict__ Cp,
                                                int N, int K) {
  __shared__ ushort_t As[3][256 * 64];
  __shared__ ushort_t Bs[3][128 * 64];
  const int tid = threadIdx.x;
  const int nx = gridDim.x;
  const int orig = blockIdx.y * nx + blockIdx.x;
  const int q = (nx * gridDim.y) >> 3;          // grids are multiples of 8
  const int swz = (orig & 7) * q + (orig >> 3);
  const int bx = swz % nx, by = swz / nx;

  const int lane = tid & 63, wv = tid >> 6;
  const int wm = wv >> 1, wn = wv & 1;          // 4M x 2N
  const int lrow = lane & 15, lk = lane >> 4;

  const ushort_t* Ab = A + (size_t)by * 256 * K;
  const ushort_t* Bb = Bt + (size_t)bx * 128 * K;

  auto stA = [&](int s, int kt, int r) {
    const int off = r * 8192 + tid * 16;        // byte offset in 32KB A tile
    const int row = off >> 7;                   // 128B rows (BK=64 bf16)
    const int ch = ((off >> 4) & 7) ^ (row & 7);
    gload16(Ab + (size_t)row * K + kt * 64 + ch * 8, (void*)&As[s][off >> 1]);
  };
  auto stB = [&](int s, int kt, int r) {
    const int off = r * 8192 + tid * 16;        // byte offset in 16KB B tile
    const int row = off >> 7;
    const int ch = ((off >> 4) & 7) ^ (row & 7);
    gload16(Bb + (size_t)row * K + kt * 64 + ch * 8, (void*)&Bs[s][off >> 1]);
  };
  auto rdA = [&](int s, int m, int ks) {
    const int r = wm * 64 + m * 16 + lrow;
    const int ch = (ks * 4 + lk) ^ (r & 7);
    return *(const bf16x8*)&As[s][r * 64 + ch * 8];
  };
  auto rdB = [&](int s, int n, int ks) {
    const int r = wn * 64 + n * 16 + lrow;
    const int ch = (ks * 4 + lk) ^ (r & 7);
    return *(const bf16x8*)&Bs[s][r * 64 + ch * 8];
  };

  f32x4 acc[4][4];
  #pragma unroll
  for (int m = 0; m < 4; ++m)
    #pragma unroll
    for (int n = 0; n < 4; ++n)
      acc[m][n] = (f32x4){0.f, 0.f, 0.f, 0.f};

  const int nt = K >> 6;
  // prologue: tile0 -> slot0 (6 rounds), tile1 -> slot1 (6 rounds)
  #pragma unroll
  for (int r = 0; r < 4; ++r) stA(0, 0, r);
  stB(0, 0, 0); stB(0, 0, 1);
  #pragma unroll
  for (int r = 0; r < 4; ++r) stA(1, 1, r);
  stB(1, 1, 0); stB(1, 1, 1);
  VMW(6);                      // tile0 landed; tile1's 6 stay in flight
  SB0(); BAR(); SB0();

  for (int t = 0; t < nt; ++t) {
    const int s = t % 3;
    const int s2 = (t + 2) % 3;
    bf16x8 av[4][2], bv[4][2];
    #pragma unroll
    for (int m = 0; m < 4; ++m)
      #pragma unroll
      for (int ks = 0; ks < 2; ++ks) av[m][ks] = rdA(s, m, ks);
    #pragma unroll
    for (int n = 0; n < 4; ++n)
      #pragma unroll
      for (int ks = 0; ks < 2; ++ks) bv[n][ks] = rdB(s, n, ks);
    if (t + 2 < nt) {
      #pragma unroll
      for (int r = 0; r < 4; ++r) stA(s2, t + 2, r);
      stB(s2, t + 2, 0); stB(s2, t + 2, 1);
    }
    __builtin_amdgcn_s_setprio(1);
    #pragma unroll
    for (int ks = 0; ks < 2; ++ks)
      #pragma unroll
      for (int m = 0; m < 4; ++m)
        #pragma unroll
        for (int n = 0; n < 4; ++n)
          acc[m][n] = __builtin_amdgcn_mfma_f32_16x16x32_bf16(av[m][ks], bv[n][ks], acc[m][n], 0, 0, 0);
    __builtin_amdgcn_s_setprio(0);
    SB0();
    // counted: retire tile t+1's 6 loads; tile t+2's 6 remain in flight
    if (t + 2 < nt) { VMW(6); } else { VMW(0); }
    SB0(); BAR(); SB0();
  }

  // epilogue: C/D layout col=lane&15, row=(lane>>4)*4+j
  #pragma unroll
  for (int m = 0; m < 4; ++m) {
    const int row0 = by * 256 + wm * 64 + m * 16 + lk * 4;
    #pragma unroll
    for (int n = 0; n < 4; ++n) {
      const int col = bx * 128 + wn * 64 + n * 16 + lrow;
      #pragma unroll
      for (int j = 0; j < 4; ++j) {
        const size_t idx = (size_t)(row0 + j) * N + col;
        if constexpr (OUT_BF16) ((ushort_t*)Cp)[idx] = f2bf(acc[m][n][j]);
        else                    ((float*)Cp)[idx] = acc[m][n][j];
      }
    }
  }
}

// ---------------- middle: h_all, router softmax, M = sum_p w (x) h ----------------
__global__ __launch_bounds__(256) void middle_kernel(const unsigned short* __restrict__ AH,
                                                     const float* __restrict__ fp,
                                                     const float* __restrict__ femb,
                                                     const float* __restrict__ Wr,
                                                     unsigned short* __restrict__ Mout,
                                                     float* __restrict__ auxout) {
  __shared__ float G[16][16];
  __shared__ float hs[4][2][128];
  __shared__ float wsm[4][2][16];
  const int tid = threadIdx.x;
  {
    const int n = tid >> 4, j = tid & 15;
    float s = 0.f;
    #pragma unroll
    for (int ds = 0; ds < 64; ++ds) s += femb[n * 64 + ds] * Wr[ds * 16 + j];
    G[n][j] = s;
  }
  const int wv = tid >> 6, l = tid & 63;
  const int t = blockIdx.x * 4 + wv;

  float p0[16], p1[16];
  #pragma unroll
  for (int n = 0; n < 16; ++n) {
    p0[n] = fp[t * 16 + n];
    p1[n] = fp[T_TOK * 16 + t * 16 + n];
  }

  float h00 = 0.f, h01 = 0.f, h10 = 0.f, h11 = 0.f;
  const unsigned short* ahrow = AH + (size_t)t * NRCOL;
  #pragma unroll
  for (int n = 0; n < 16; ++n) {
    const unsigned int v = *(const unsigned int*)(ahrow + n * 128 + 2 * l);
    const float a0 = bfbits2f(v & 0xffffu);
    const float a1 = bfbits2f(v >> 16);
    h00 += a0 * p0[n]; h01 += a1 * p0[n];
    h10 += a0 * p1[n]; h11 += a1 * p1[n];
  }
  hs[wv][0][2 * l] = h00; hs[wv][0][2 * l + 1] = h01;
  hs[wv][1][2 * l] = h10; hs[wv][1][2 * l + 1] = h11;
  __syncthreads();

  if (l < 32) {
    const int p = l >> 4, j = l & 15;
    float s = 0.f;
    #pragma unroll
    for (int n = 0; n < 16; ++n) s += (p ? p1[n] : p0[n]) * G[n][j];
    for (int r = 0; r < 128; ++r) s += hs[wv][p][r] * Wr[(64 + r) * 16 + j];
    float mx = s;
    #pragma unroll
    for (int d = 1; d < 16; d <<= 1) mx = fmaxf(mx, __shfl_xor(mx, d, 64));
    const float e = __expf(s - mx);
    float sum = e;
    #pragma unroll
    for (int d = 1; d < 16; d <<= 1) sum += __shfl_xor(sum, d, 64);
    wsm[wv][p][j] = e / sum;
  }
  __syncthreads();

  unsigned short* mrow = Mout + (size_t)t * NRCOL;
  #pragma unroll
  for (int n = 0; n < 16; ++n) {
    const float w0 = wsm[wv][0][n], w1 = wsm[wv][1][n];
    const float m0 = w0 * h00 + w1 * h10;
    const float m1 = w0 * h01 + w1 * h11;
    const unsigned int pk = (unsigned)f2bf(m0) | ((unsigned)f2bf(m1) << 16);
    *(unsigned int*)(mrow + n * 128 + 2 * l) = pk;
  }
  if (blockIdx.x == 0 && tid == 0) auxout[0] = 0.f;
}

extern "C" void kernel_launch(void* const* d_in, const int* in_sizes, int n_in,
                              void* d_out, int out_size, void* d_ws, size_t ws_size,
                              hipStream_t stream) {
  const float* x    = (const float*)d_in[0];
  const float* fp   = (const float*)d_in[1];
  const float* fk   = (const float*)d_in[2];
  const float* rk   = (const float*)d_in[3];
  const float* femb = (const float*)d_in[4];
  const float* Wr   = (const float*)d_in[5];
  float* out = (float*)d_out;

  char* ws = (char*)d_ws;
  unsigned short* Xbf = (unsigned short*)ws;
  unsigned short* W1t = (unsigned short*)(ws + 16u * 1024 * 1024);
  unsigned short* Mb  = (unsigned short*)ws;
  unsigned short* W2t = (unsigned short*)(ws + 32u * 1024 * 1024);
  unsigned short* AH  = (unsigned short*)(ws + 36u * 1024 * 1024);

  cvt_f32_bf16<<<2048, 256, 0, stream>>>(x, Xbf, (T_TOK * DIM) / 4);
  tcvt<<<dim3(128 / 32, 1024 / 32, 16), 256, 0, stream>>>(fk, W1t, 1024, 128,
                                                          1024L * 128, 128L * 1024);
  tcvt<<<dim3(1024 / 32, 2048 / 32, 1), 256, 0, stream>>>(rk, W2t, 2048, 1024, 0, 0);
  // all_h = Xbf @ W1t^T -> AH bf16 [8192][2048]
  gemmT<true><<<dim3(NRCOL / 128, T_TOK / 256), 512, 0, stream>>>(Xbf, W1t, AH,
                                                                  NRCOL, DIM);
  middle_kernel<<<T_TOK / 4, 256, 0, stream>>>(AH, fp, femb, Wr, Mb, out + 8388608);
  // output = Mb @ W2t^T -> f32 d_out [8192][1024]
  gemmT<false><<<dim3(DIM / 128, T_TOK / 256), 512, 0, stream>>>(Mb, W2t, out,
                                                                 DIM, NRCOL);
}